// Round 11
// baseline (698.880 us; speedup 1.0000x reference)
//
#include <hip/hip_runtime.h>

// Diffeomorphic transform (scaling & squaring), 7 steps.
// flow: [1, 3, 192, 192, 192] fp32, c=0 -> z disp, c=1 -> y, c=2 -> x.
// out = f + trilinear_sample(f, voxel + f*(size-1)/2), border clamp,
// align_corners=True (identity unnormalizes to voxel index).
//
// R9 (kept): exact fp32 float4 records in 2x2x2-voxel tiles, tiled thread
// mapping, XCD z-chunk swizzle. R10 (kept): MLP fence so all gathers issue
// before any FMA. R11: mid steps process TWO voxels/thread -> 16 gather
// loads in flight per wave. R10's +14% from the fence shows the floor is
// latency x concurrency (Little's law: ~216 outstanding lines/CU at 8/wave);
// 2 voxels/thread raises in-flight ~1.5x even after the VGPR-driven
// occupancy drop. it1/it7 stay 1-voxel (planar decode/encode ends).

constexpr int DD = 192, HH = 192, WW = 192;
constexpr int NN = DD * HH * WW;
constexpr int NB = NN / 256;       // 27648 blocks (1-voxel kernel)
constexpr int NB2 = NN / 512;      // 13824 blocks (2-voxel kernel)
constexpr int NXCD = 8;
constexpr int CHUNK = NB / NXCD;   // 3456
constexpr int CHUNK2 = NB2 / NXCD; // 1728
constexpr int TT = WW / 2;         // 96 tiles per axis

struct F3 { float x, y, z; };      // 12B fallback record
typedef float f4 __attribute__((ext_vector_type(4)));

// Record index (units of f4) in the 2x2x2-tiled layout. Bijection on [0,NN).
__device__ __forceinline__ int rec_addr(int z, int y, int x) {
    return ((((z >> 1) * TT + (y >> 1)) * TT + (x >> 1)) << 3)
         + (((z & 1) << 2) | ((y & 1) << 1) | (x & 1));
}

__device__ __forceinline__ void rec_decode(int gid, int& w, int& h, int& d) {
    int slot = gid & 7;
    int tile = gid >> 3;
    int tx = tile % TT;
    int t2 = tile / TT;
    int ty = t2 % TT;
    int tz = t2 / TT;
    w = (tx << 1) | (slot & 1);
    h = (ty << 1) | ((slot >> 1) & 1);
    d = (tz << 1) | (slot >> 2);
}

struct Samp {
    int a000, a001, a010, a011, a100, a101, a110, a111;
    float w000, w001, w010, w011, w100, w101, w110, w111;
    float f0, f1, f2;
};

__device__ __forceinline__ Samp setup(int w, int h, int d, f4 own, float scale) {
    Samp s;
    s.f0 = own.x * scale; s.f1 = own.y * scale; s.f2 = own.z * scale;
    float x = fminf(fmaxf((float)w + s.f2 * (0.5f * (WW - 1)), 0.0f), (float)(WW - 1));
    float y = fminf(fmaxf((float)h + s.f1 * (0.5f * (HH - 1)), 0.0f), (float)(HH - 1));
    float z = fminf(fmaxf((float)d + s.f0 * (0.5f * (DD - 1)), 0.0f), (float)(DD - 1));
    int x0 = (int)x;  float wx = x - (float)x0;
    int y0 = (int)y;  float wy = y - (float)y0;
    int z0 = (int)z;  float wz = z - (float)z0;
    int x1 = min(x0 + 1, WW - 1);
    int y1 = min(y0 + 1, HH - 1);
    int z1 = min(z0 + 1, DD - 1);
    float ox = 1.0f - wx, oy = 1.0f - wy, oz = 1.0f - wz;
    s.w000 = ox * oy * oz; s.w001 = wx * oy * oz;
    s.w010 = ox * wy * oz; s.w011 = wx * wy * oz;
    s.w100 = ox * oy * wz; s.w101 = wx * oy * wz;
    s.w110 = ox * wy * wz; s.w111 = wx * wy * wz;
    s.a000 = rec_addr(z0, y0, x0); s.a001 = rec_addr(z0, y0, x1);
    s.a010 = rec_addr(z0, y1, x0); s.a011 = rec_addr(z0, y1, x1);
    s.a100 = rec_addr(z1, y0, x0); s.a101 = rec_addr(z1, y0, x1);
    s.a110 = rec_addr(z1, y1, x0); s.a111 = rec_addr(z1, y1, x1);
    return s;
}

__device__ __forceinline__ f4 interp(const Samp& s,
    f4 c000, f4 c001, f4 c010, f4 c011, f4 c100, f4 c101, f4 c110, f4 c111,
    float scale)
{
    float v0 = s.w000 * c000.x + s.w001 * c001.x + s.w010 * c010.x + s.w011 * c011.x
             + s.w100 * c100.x + s.w101 * c101.x + s.w110 * c110.x + s.w111 * c111.x;
    float v1 = s.w000 * c000.y + s.w001 * c001.y + s.w010 * c010.y + s.w011 * c011.y
             + s.w100 * c100.y + s.w101 * c101.y + s.w110 * c110.y + s.w111 * c111.y;
    float v2 = s.w000 * c000.z + s.w001 * c001.z + s.w010 * c010.z + s.w011 * c011.z
             + s.w100 * c100.z + s.w101 * c101.z + s.w110 * c110.z + s.w111 * c111.z;
    f4 o = { s.f0 + scale * v0, s.f1 + scale * v1, s.f2 + scale * v2, 0.0f };
    return o;
}

// ---- mid steps: tiled f4 -> tiled f4, 2 voxels per thread ----
__global__ __launch_bounds__(256) void diffeo_mid2(
    const f4* __restrict__ src, f4* __restrict__ dst)
{
    int bid = blockIdx.x;
    int swz = (bid & (NXCD - 1)) * CHUNK2 + (bid >> 3);
    int gidA = swz * 512 + threadIdx.x;
    int gidB = gidA + 256;

    int wA, hA, dA, wB, hB, dB;
    rec_decode(gidA, wA, hA, dA);
    rec_decode(gidB, wB, hB, dB);

    f4 ownA = src[gidA];
    f4 ownB = src[gidB];

    Samp sA = setup(wA, hA, dA, ownA, 1.0f);
    Samp sB = setup(wB, hB, dB, ownB, 1.0f);

    f4 cA000 = src[sA.a000], cA001 = src[sA.a001];
    f4 cA010 = src[sA.a010], cA011 = src[sA.a011];
    f4 cA100 = src[sA.a100], cA101 = src[sA.a101];
    f4 cA110 = src[sA.a110], cA111 = src[sA.a111];
    f4 cB000 = src[sB.a000], cB001 = src[sB.a001];
    f4 cB010 = src[sB.a010], cB011 = src[sB.a011];
    f4 cB100 = src[sB.a100], cB101 = src[sB.a101];
    f4 cB110 = src[sB.a110], cB111 = src[sB.a111];
    // MLP fence: all 16 gathers issue before any FMA consumes one.
    asm volatile("" : "+v"(cA000), "+v"(cA001), "+v"(cA010), "+v"(cA011),
                      "+v"(cA100), "+v"(cA101), "+v"(cA110), "+v"(cA111),
                      "+v"(cB000), "+v"(cB001), "+v"(cB010), "+v"(cB011),
                      "+v"(cB100), "+v"(cB101), "+v"(cB110), "+v"(cB111));

    dst[gidA] = interp(sA, cA000, cA001, cA010, cA011, cA100, cA101, cA110, cA111, 1.0f);
    dst[gidB] = interp(sB, cB000, cB001, cB010, cB011, cB100, cB101, cB110, cB111, 1.0f);
}

// ---- end steps: planar fp32 <-> tiled f4 (1 voxel/thread) ----
// Modes: 0 = planar fp32 (stride NN/channel), 1 = tiled f4, 2 = F3 12B row-major.
template <int SM, int DM>
__global__ __launch_bounds__(256) void diffeo_step(
    const void* __restrict__ srcv, void* __restrict__ dstv, float scale)
{
    int bid = blockIdx.x;
    int swz = (bid & (NXCD - 1)) * CHUNK + (bid >> 3);
    int gid = swz * 256 + threadIdx.x;

    int w, h, d;
    if constexpr (SM == 1 || DM == 1) {
        rec_decode(gid, w, h, d);
    } else {
        w = gid % WW;
        int t = gid / WW;
        h = t % HH;
        d = t / HH;
    }
    int idx = (d * HH + h) * WW + w;   // row-major voxel index (planar I/O)

    f4 own;
    if constexpr (SM == 0) {
        const float* src = (const float*)srcv;
        own = f4{ src[idx], src[idx + NN], src[idx + 2 * NN], 0.0f };
    } else if constexpr (SM == 1) {
        own = ((const f4*)srcv)[gid];
    } else {
        const F3* s3 = (const F3*)srcv;
        F3 o3 = s3[gid];
        own = f4{ o3.x, o3.y, o3.z, 0.0f };
    }

    Samp s = setup(w, h, d, own, scale);

    f4 o;
    if constexpr (SM == 0) {
        const float* src = (const float*)srcv;
        // addresses in Samp are tiled; recompute row-major here from scratch
        // (SM==0 only used for it1 where gathers are near-local / L1-hit).
        float x = fminf(fmaxf((float)w + s.f2 * (0.5f * (WW - 1)), 0.0f), (float)(WW - 1));
        float y = fminf(fmaxf((float)h + s.f1 * (0.5f * (HH - 1)), 0.0f), (float)(HH - 1));
        float z = fminf(fmaxf((float)d + s.f0 * (0.5f * (DD - 1)), 0.0f), (float)(DD - 1));
        int x0 = (int)x, y0 = (int)y, z0 = (int)z;
        int x1 = min(x0 + 1, WW - 1), y1 = min(y0 + 1, HH - 1), z1 = min(z0 + 1, DD - 1);
        int i000 = (z0 * HH + y0) * WW + x0, i001 = (z0 * HH + y0) * WW + x1;
        int i010 = (z0 * HH + y1) * WW + x0, i011 = (z0 * HH + y1) * WW + x1;
        int i100 = (z1 * HH + y0) * WW + x0, i101 = (z1 * HH + y0) * WW + x1;
        int i110 = (z1 * HH + y1) * WW + x0, i111 = (z1 * HH + y1) * WW + x1;
        float v[3];
#pragma unroll
        for (int c = 0; c < 3; ++c) {
            const float* p = src + c * NN;
            v[c] = s.w000 * p[i000] + s.w001 * p[i001] +
                   s.w010 * p[i010] + s.w011 * p[i011] +
                   s.w100 * p[i100] + s.w101 * p[i101] +
                   s.w110 * p[i110] + s.w111 * p[i111];
        }
        o = f4{ s.f0 + scale * v[0], s.f1 + scale * v[1], s.f2 + scale * v[2], 0.0f };
    } else if constexpr (SM == 1) {
        const f4* s4 = (const f4*)srcv;
        f4 c000 = s4[s.a000], c001 = s4[s.a001];
        f4 c010 = s4[s.a010], c011 = s4[s.a011];
        f4 c100 = s4[s.a100], c101 = s4[s.a101];
        f4 c110 = s4[s.a110], c111 = s4[s.a111];
        asm volatile("" : "+v"(c000), "+v"(c001), "+v"(c010), "+v"(c011),
                          "+v"(c100), "+v"(c101), "+v"(c110), "+v"(c111));
        o = interp(s, c000, c001, c010, c011, c100, c101, c110, c111, scale);
    } else {
        const F3* s3 = (const F3*)srcv;
        // F3 row-major fallback: row-major addresses
        int x0, y0, z0, x1, y1, z1;
        {
            float x = fminf(fmaxf((float)w + s.f2 * (0.5f * (WW - 1)), 0.0f), (float)(WW - 1));
            float y = fminf(fmaxf((float)h + s.f1 * (0.5f * (HH - 1)), 0.0f), (float)(HH - 1));
            float z = fminf(fmaxf((float)d + s.f0 * (0.5f * (DD - 1)), 0.0f), (float)(DD - 1));
            x0 = (int)x; y0 = (int)y; z0 = (int)z;
            x1 = min(x0 + 1, WW - 1); y1 = min(y0 + 1, HH - 1); z1 = min(z0 + 1, DD - 1);
        }
        F3 c000 = s3[(z0 * HH + y0) * WW + x0], c001 = s3[(z0 * HH + y0) * WW + x1];
        F3 c010 = s3[(z0 * HH + y1) * WW + x0], c011 = s3[(z0 * HH + y1) * WW + x1];
        F3 c100 = s3[(z1 * HH + y0) * WW + x0], c101 = s3[(z1 * HH + y0) * WW + x1];
        F3 c110 = s3[(z1 * HH + y1) * WW + x0], c111 = s3[(z1 * HH + y1) * WW + x1];
        float v0 = s.w000 * c000.x + s.w001 * c001.x + s.w010 * c010.x + s.w011 * c011.x
                 + s.w100 * c100.x + s.w101 * c101.x + s.w110 * c110.x + s.w111 * c111.x;
        float v1 = s.w000 * c000.y + s.w001 * c001.y + s.w010 * c010.y + s.w011 * c011.y
                 + s.w100 * c100.y + s.w101 * c101.y + s.w110 * c110.y + s.w111 * c111.y;
        float v2 = s.w000 * c000.z + s.w001 * c001.z + s.w010 * c010.z + s.w011 * c011.z
                 + s.w100 * c100.z + s.w101 * c101.z + s.w110 * c110.z + s.w111 * c111.z;
        o = f4{ s.f0 + scale * v0, s.f1 + scale * v1, s.f2 + scale * v2, 0.0f };
    }

    if constexpr (DM == 0) {
        float* dst = (float*)dstv;
        dst[idx] = o.x; dst[idx + NN] = o.y; dst[idx + 2 * NN] = o.z;
    } else if constexpr (DM == 1) {
        ((f4*)dstv)[gid] = o;
    } else {
        F3* d3 = (F3*)dstv;
        F3 of = { o.x, o.y, o.z };
        d3[gid] = of;
    }
}

extern "C" void kernel_launch(void* const* d_in, const int* in_sizes, int n_in,
                              void* d_out, int out_size, void* d_ws, size_t ws_size,
                              hipStream_t stream) {
    const void* in = d_in[0];
    void* out = d_out;
    const float inv = 1.0f / 128.0f;  // 2^-TIME_STEP, TIME_STEP=7

    if (ws_size >= (size_t)NN * 32) {
        f4* qa = (f4*)d_ws;        // buffer A (113 MB)
        f4* qb = (f4*)d_ws + NN;   // buffer B (113 MB)
        diffeo_step<0, 1><<<NB, 256, 0, stream>>>(in, qa, inv);    // it1
        diffeo_mid2<<<NB2, 256, 0, stream>>>(qa, qb);              // it2
        diffeo_mid2<<<NB2, 256, 0, stream>>>(qb, qa);              // it3
        diffeo_mid2<<<NB2, 256, 0, stream>>>(qa, qb);              // it4
        diffeo_mid2<<<NB2, 256, 0, stream>>>(qb, qa);              // it5
        diffeo_mid2<<<NB2, 256, 0, stream>>>(qa, qb);              // it6
        diffeo_step<1, 0><<<NB, 256, 0, stream>>>(qb, out, 1.0f);  // it7
    } else {
        // Fallback: F3 12B ping-pong (R3/R4 proven path).
        void* ws = d_ws;
        diffeo_step<0, 2><<<NB, 256, 0, stream>>>(in,  out, inv);
        diffeo_step<2, 2><<<NB, 256, 0, stream>>>(out, ws,  1.0f);
        diffeo_step<2, 2><<<NB, 256, 0, stream>>>(ws,  out, 1.0f);
        diffeo_step<2, 2><<<NB, 256, 0, stream>>>(out, ws,  1.0f);
        diffeo_step<2, 2><<<NB, 256, 0, stream>>>(ws,  out, 1.0f);
        diffeo_step<2, 2><<<NB, 256, 0, stream>>>(out, ws,  1.0f);
        diffeo_step<2, 0><<<NB, 256, 0, stream>>>(ws,  out, 1.0f);
    }
}

// Round 12
// 649.824 us; speedup vs baseline: 1.0755x; 1.0755x over previous
//
#include <hip/hip_runtime.h>

// Diffeomorphic transform (scaling & squaring), 7 steps.
// flow: [1, 3, 192, 192, 192] fp32, c=0 -> z disp, c=1 -> y, c=2 -> x.
// out = f + trilinear_sample(f, voxel + f*(size-1)/2), border clamp,
// align_corners=True (identity unnormalizes to voxel index).
//
// R12: x-duplicated 32B records {v(x), v(x+1)}, lines = y-pairs:
//   L(z,y,x) = ((z*96 + (y>>1))*192 + x)*2 + (y&1)   [units of 32B records]
// 64B line = {y-even, y-odd} records at same (z,x). Trilinear footprint =
// 4 records -> E[3.0] lines vs E[4.5] for the 2x2x2-tiled f4 layout (-33%
// L3 fill traffic; R10/R11 showed mids are L3-latency/fill bound at ~2GB per
// dispatch). Writes: thread x stores lo(rec x) + hi(rec x-1) (+self-hi at
// x=W-1) -- all within one wave, no temporally-distant partial lines (R8
// lesson). Needs ws >= 453MB (2 x 226.5MB ping-pong): runtime-gated,
// falls back to the exact R10 path (650us) otherwise.
// Kept: XCD swizzle (R2), exact fp32 (R6/R7 lesson), MLP asm fence (R10).

constexpr int DD = 192, HH = 192, WW = 192;
constexpr int NN = DD * HH * WW;
constexpr int NXCD = 8;
constexpr int HP = HH / 2;          // 96 y-pairs
constexpr int NBX = DD * HP;        // 18432 blocks of 384 (xdup kernels)
constexpr int CHUNKX = NBX / NXCD;  // 2304
// fallback (R10 tiled) geometry
constexpr int NB = NN / 256;        // 27648
constexpr int CHUNK = NB / NXCD;    // 3456
constexpr int TT = WW / 2;          // 96

typedef float f4 __attribute__((ext_vector_type(4)));
constexpr float INV = 1.0f / 128.0f;   // 2^-TIME_STEP

// ---------------- xdup layout helpers ----------------
__device__ __forceinline__ int xdup_L(int z, int y, int x) {
    return ((z * HP + (y >> 1)) * WW + x) * 2 + (y & 1);  // record index
}

struct Pos {
    int x0, y0, z0, x1, y1, z1;
    float wx, wy, wz;
};

__device__ __forceinline__ Pos posn(int w, int h, int d, float f0, float f1, float f2) {
    Pos p;
    float x = fminf(fmaxf((float)w + f2 * (0.5f * (WW - 1)), 0.0f), (float)(WW - 1));
    float y = fminf(fmaxf((float)h + f1 * (0.5f * (HH - 1)), 0.0f), (float)(HH - 1));
    float z = fminf(fmaxf((float)d + f0 * (0.5f * (DD - 1)), 0.0f), (float)(DD - 1));
    p.x0 = (int)x; p.wx = x - (float)p.x0;
    p.y0 = (int)y; p.wy = y - (float)p.y0;
    p.z0 = (int)z; p.wz = z - (float)p.z0;
    p.x1 = min(p.x0 + 1, WW - 1);
    p.y1 = min(p.y0 + 1, HH - 1);
    p.z1 = min(p.z0 + 1, DD - 1);
    return p;
}

// gather 8 f4 (4 records) from xdup src and trilinear-combine
__device__ __forceinline__ f4 xdup_sample(const f4* __restrict__ src, const Pos& p) {
    int L00 = xdup_L(p.z0, p.y0, p.x0);
    int L01 = xdup_L(p.z0, p.y1, p.x0);
    int L10 = xdup_L(p.z1, p.y0, p.x0);
    int L11 = xdup_L(p.z1, p.y1, p.x0);
    f4 a0 = src[2 * L00], a1 = src[2 * L00 + 1];
    f4 b0 = src[2 * L01], b1 = src[2 * L01 + 1];
    f4 c0 = src[2 * L10], c1 = src[2 * L10 + 1];
    f4 d0 = src[2 * L11], d1 = src[2 * L11 + 1];
    // MLP fence: all 8 gathers issue before any FMA consumes one (R10 win).
    asm volatile("" : "+v"(a0), "+v"(a1), "+v"(b0), "+v"(b1),
                      "+v"(c0), "+v"(c1), "+v"(d0), "+v"(d1));
    float ox = 1.0f - p.wx, oy = 1.0f - p.wy, oz = 1.0f - p.wz;
    f4 r00 = a0 * ox + a1 * p.wx;   // (z0, y0)
    f4 r01 = b0 * ox + b1 * p.wx;   // (z0, y1)
    f4 r10 = c0 * ox + c1 * p.wx;   // (z1, y0)
    f4 r11 = d0 * ox + d1 * p.wx;   // (z1, y1)
    return (r00 * oy + r01 * p.wy) * oz + (r10 * oy + r11 * p.wy) * p.wz;
}

// scatter own value into xdup dst: lo(rec x), hi(rec x-1), self-hi at border
__device__ __forceinline__ void xdup_store(f4* __restrict__ dst, int L, int x, f4 o) {
    dst[2 * L] = o;                       // lo of own record
    if (x > 0)       dst[2 * L - 3] = o;  // hi of rec (x-1): 2*(L-2)+1
    if (x == WW - 1) dst[2 * L + 1] = o;  // border clamp dup
}

// block/thread -> (z, y, x, L) for 384-thread xdup kernels
__device__ __forceinline__ void xdup_decode(int bid, int tid,
                                            int& z, int& y, int& x, int& L) {
    int swz = (bid & (NXCD - 1)) * CHUNKX + (bid >> 3);
    z = swz / HP;
    int yp = swz - z * HP;
    int p = tid & 1;
    x = tid >> 1;
    y = 2 * yp + p;
    L = (swz * WW + x) * 2 + p;
}

// ---- it1: planar fp32 -> xdup (gathers planar, disp < 1 voxel: local) ----
__global__ __launch_bounds__(384) void diffeo_in_x(
    const float* __restrict__ src, f4* __restrict__ dst)
{
    int z, y, x, L;
    xdup_decode(blockIdx.x, threadIdx.x, z, y, x, L);
    int idx = (z * HH + y) * WW + x;

    float f0 = src[idx] * INV;
    float f1 = src[idx + NN] * INV;
    float f2 = src[idx + 2 * NN] * INV;
    Pos p = posn(x, y, z, f0, f1, f2);

    int i000 = (p.z0 * HH + p.y0) * WW + p.x0, i001 = (p.z0 * HH + p.y0) * WW + p.x1;
    int i010 = (p.z0 * HH + p.y1) * WW + p.x0, i011 = (p.z0 * HH + p.y1) * WW + p.x1;
    int i100 = (p.z1 * HH + p.y0) * WW + p.x0, i101 = (p.z1 * HH + p.y0) * WW + p.x1;
    int i110 = (p.z1 * HH + p.y1) * WW + p.x0, i111 = (p.z1 * HH + p.y1) * WW + p.x1;
    float ox = 1.0f - p.wx, oy = 1.0f - p.wy, oz = 1.0f - p.wz;
    float w000 = ox * oy * oz, w001 = p.wx * oy * oz;
    float w010 = ox * p.wy * oz, w011 = p.wx * p.wy * oz;
    float w100 = ox * oy * p.wz, w101 = p.wx * oy * p.wz;
    float w110 = ox * p.wy * p.wz, w111 = p.wx * p.wy * p.wz;
    float v[3];
#pragma unroll
    for (int c = 0; c < 3; ++c) {
        const float* s = src + c * NN;
        v[c] = w000 * s[i000] + w001 * s[i001] + w010 * s[i010] + w011 * s[i011]
             + w100 * s[i100] + w101 * s[i101] + w110 * s[i110] + w111 * s[i111];
    }
    f4 o = { f0 + INV * v[0], f1 + INV * v[1], f2 + INV * v[2], 0.0f };
    xdup_store(dst, L, x, o);
}

// ---- it2..it6: xdup -> xdup ----
__global__ __launch_bounds__(384) void diffeo_mid_x(
    const f4* __restrict__ src, f4* __restrict__ dst)
{
    int z, y, x, L;
    xdup_decode(blockIdx.x, threadIdx.x, z, y, x, L);
    f4 own = src[2 * L];
    Pos p = posn(x, y, z, own.x, own.y, own.z);
    f4 vv = xdup_sample(src, p);
    f4 o = own + vv;
    o.w = 0.0f;
    xdup_store(dst, L, x, o);
}

// ---- it7: xdup -> planar fp32 ----
__global__ __launch_bounds__(384) void diffeo_out_x(
    const f4* __restrict__ src, float* __restrict__ dst)
{
    int z, y, x, L;
    xdup_decode(blockIdx.x, threadIdx.x, z, y, x, L);
    int idx = (z * HH + y) * WW + x;
    f4 own = src[2 * L];
    Pos p = posn(x, y, z, own.x, own.y, own.z);
    f4 vv = xdup_sample(src, p);
    dst[idx]          = own.x + vv.x;
    dst[idx + NN]     = own.y + vv.y;
    dst[idx + 2 * NN] = own.z + vv.z;
}

// ================= R10 fallback: 2x2x2-tiled f4 =================
__device__ __forceinline__ int rec_addr(int z, int y, int x) {
    return ((((z >> 1) * TT + (y >> 1)) * TT + (x >> 1)) << 3)
         + (((z & 1) << 2) | ((y & 1) << 1) | (x & 1));
}

// Modes: 0 = planar fp32, 1 = tiled f4.
template <int SM, int DM>
__global__ __launch_bounds__(256) void diffeo_step(
    const void* __restrict__ srcv, void* __restrict__ dstv, float scale)
{
    int bid = blockIdx.x;
    int swz = (bid & (NXCD - 1)) * CHUNK + (bid >> 3);
    int gid = swz * 256 + threadIdx.x;

    int w, h, d;
    {
        int slot = gid & 7;
        int tile = gid >> 3;
        int tx = tile % TT;
        int t2 = tile / TT;
        int ty = t2 % TT;
        int tz = t2 / TT;
        w = (tx << 1) | (slot & 1);
        h = (ty << 1) | ((slot >> 1) & 1);
        d = (tz << 1) | (slot >> 2);
    }
    int idx = (d * HH + h) * WW + w;

    f4 own;
    if constexpr (SM == 0) {
        const float* src = (const float*)srcv;
        own = f4{ src[idx], src[idx + NN], src[idx + 2 * NN], 0.0f };
    } else {
        own = ((const f4*)srcv)[gid];
    }
    float f0 = own.x * scale, f1 = own.y * scale, f2 = own.z * scale;
    Pos p = posn(w, h, d, f0, f1, f2);
    float ox = 1.0f - p.wx, oy = 1.0f - p.wy, oz = 1.0f - p.wz;
    float w000 = ox * oy * oz, w001 = p.wx * oy * oz;
    float w010 = ox * p.wy * oz, w011 = p.wx * p.wy * oz;
    float w100 = ox * oy * p.wz, w101 = p.wx * oy * p.wz;
    float w110 = ox * p.wy * p.wz, w111 = p.wx * p.wy * p.wz;

    float v0, v1, v2;
    if constexpr (SM == 0) {
        const float* src = (const float*)srcv;
        int i000 = (p.z0 * HH + p.y0) * WW + p.x0, i001 = (p.z0 * HH + p.y0) * WW + p.x1;
        int i010 = (p.z0 * HH + p.y1) * WW + p.x0, i011 = (p.z0 * HH + p.y1) * WW + p.x1;
        int i100 = (p.z1 * HH + p.y0) * WW + p.x0, i101 = (p.z1 * HH + p.y0) * WW + p.x1;
        int i110 = (p.z1 * HH + p.y1) * WW + p.x0, i111 = (p.z1 * HH + p.y1) * WW + p.x1;
        float acc[3];
#pragma unroll
        for (int c = 0; c < 3; ++c) {
            const float* s = src + c * NN;
            acc[c] = w000 * s[i000] + w001 * s[i001] + w010 * s[i010] + w011 * s[i011]
                   + w100 * s[i100] + w101 * s[i101] + w110 * s[i110] + w111 * s[i111];
        }
        v0 = acc[0]; v1 = acc[1]; v2 = acc[2];
    } else {
        const f4* s4 = (const f4*)srcv;
        f4 c000 = s4[rec_addr(p.z0, p.y0, p.x0)], c001 = s4[rec_addr(p.z0, p.y0, p.x1)];
        f4 c010 = s4[rec_addr(p.z0, p.y1, p.x0)], c011 = s4[rec_addr(p.z0, p.y1, p.x1)];
        f4 c100 = s4[rec_addr(p.z1, p.y0, p.x0)], c101 = s4[rec_addr(p.z1, p.y0, p.x1)];
        f4 c110 = s4[rec_addr(p.z1, p.y1, p.x0)], c111 = s4[rec_addr(p.z1, p.y1, p.x1)];
        asm volatile("" : "+v"(c000), "+v"(c001), "+v"(c010), "+v"(c011),
                          "+v"(c100), "+v"(c101), "+v"(c110), "+v"(c111));
        v0 = w000 * c000.x + w001 * c001.x + w010 * c010.x + w011 * c011.x
           + w100 * c100.x + w101 * c101.x + w110 * c110.x + w111 * c111.x;
        v1 = w000 * c000.y + w001 * c001.y + w010 * c010.y + w011 * c011.y
           + w100 * c100.y + w101 * c101.y + w110 * c110.y + w111 * c111.y;
        v2 = w000 * c000.z + w001 * c001.z + w010 * c010.z + w011 * c011.z
           + w100 * c100.z + w101 * c101.z + w110 * c110.z + w111 * c111.z;
    }

    f4 o = { f0 + scale * v0, f1 + scale * v1, f2 + scale * v2, 0.0f };
    if constexpr (DM == 0) {
        float* dst = (float*)dstv;
        dst[idx] = o.x; dst[idx + NN] = o.y; dst[idx + 2 * NN] = o.z;
    } else {
        ((f4*)dstv)[gid] = o;
    }
}

extern "C" void kernel_launch(void* const* d_in, const int* in_sizes, int n_in,
                              void* d_out, int out_size, void* d_ws, size_t ws_size,
                              hipStream_t stream) {
    const void* in = d_in[0];
    void* out = d_out;

    if (ws_size >= (size_t)NN * 64) {
        // xdup path: two 226.5MB buffers
        f4* qa = (f4*)d_ws;            // buffer A
        f4* qb = (f4*)d_ws + 2 * NN;   // buffer B
        diffeo_in_x <<<NBX, 384, 0, stream>>>((const float*)in, qa);  // it1
        diffeo_mid_x<<<NBX, 384, 0, stream>>>(qa, qb);                // it2
        diffeo_mid_x<<<NBX, 384, 0, stream>>>(qb, qa);                // it3
        diffeo_mid_x<<<NBX, 384, 0, stream>>>(qa, qb);                // it4
        diffeo_mid_x<<<NBX, 384, 0, stream>>>(qb, qa);                // it5
        diffeo_mid_x<<<NBX, 384, 0, stream>>>(qa, qb);                // it6
        diffeo_out_x<<<NBX, 384, 0, stream>>>(qb, (float*)out);       // it7
    } else {
        // R10 fallback: tiled f4 ping-pong (proven 650us).
        f4* qa = (f4*)d_ws;
        f4* qb = (f4*)d_ws + NN;
        diffeo_step<0, 1><<<NB, 256, 0, stream>>>(in, qa, INV);    // it1
        diffeo_step<1, 1><<<NB, 256, 0, stream>>>(qa, qb, 1.0f);   // it2
        diffeo_step<1, 1><<<NB, 256, 0, stream>>>(qb, qa, 1.0f);   // it3
        diffeo_step<1, 1><<<NB, 256, 0, stream>>>(qa, qb, 1.0f);   // it4
        diffeo_step<1, 1><<<NB, 256, 0, stream>>>(qb, qa, 1.0f);   // it5
        diffeo_step<1, 1><<<NB, 256, 0, stream>>>(qa, qb, 1.0f);   // it6
        diffeo_step<1, 0><<<NB, 256, 0, stream>>>(qb, out, 1.0f);  // it7
    }
}